// Round 1
// baseline (650.795 us; speedup 1.0000x reference)
//
#include <hip/hip_runtime.h>

// TAdaConv2d: out[b,co,t,h,w] = bias[co] +
//   sum_{ci,ky,kx} x[b,ci,t,h+ky-1,w+kx-1] * alpha[b,ci,t] * weight[co,ci,ky,kx]
// Strategy: fold alpha into x at LDS-stage time; then plain 3x3 conv per (b,t).
// Block = one (b,t) image x one 16x16 spatial tile x all 64 c_out.
// Thread = 8 c_out x 8 pixels register tile (64 accumulators).

#define BATCH 8
#define CIN   64
#define COUT  64
#define TT    16
#define HH    64
#define WW    64
#define TILE  16
#define CI_CHUNK 8
#define XS_H  18          // TILE + 2 halo
#define XS_W  20          // 18 padded to 20 (float4 alignment; gcd(20,32)=4 banks)
#define CO_PAD 68         // 64 padded to 68 (float4-aligned, stride 68 = 4 mod 32)

__global__ __launch_bounds__(256) void tada_conv_f32(
    const float* __restrict__ x, const float* __restrict__ alpha,
    const float* __restrict__ weight, const float* __restrict__ bias,
    float* __restrict__ out)
{
    __shared__ float xs[CI_CHUNK][XS_H][XS_W];   // 11.25 KB
    __shared__ float ws[CI_CHUNK][9][CO_PAD];    // 19.1 KB

    const int tid  = threadIdx.x;
    const int blk  = blockIdx.x;
    const int tile = blk & 15;        // 4x4 spatial tiles
    const int bt   = blk >> 4;        // 0..127
    const int t    = bt & (TT - 1);
    const int b    = bt >> 4;
    const int th   = tile >> 2;
    const int tw   = tile & 3;
    const int h0   = th * TILE;
    const int w0   = tw * TILE;

    // thread tile mapping: 8 co-groups x 32 pixel-groups
    const int cg    = tid >> 5;       // 0..7
    const int pg    = tid & 31;       // 0..31
    const int co0   = cg * 8;
    const int prow  = pg >> 1;        // 0..15
    const int pcol0 = (pg & 1) * 8;   // 0 or 8

    float acc[8][8];
#pragma unroll
    for (int i = 0; i < 8; ++i)
#pragma unroll
        for (int j = 0; j < 8; ++j) acc[i][j] = 0.f;

    for (int ci0 = 0; ci0 < CIN; ci0 += CI_CHUNK) {
        // ---- stage x tile (alpha folded in), zero-padded halo ----
        for (int i = tid; i < CI_CHUNK * 18 * 18; i += 256) {
            int cil  = i / 324;
            int r    = i - cil * 324;
            int y    = r / 18;
            int xcol = r - y * 18;
            int ci   = ci0 + cil;
            int gh   = h0 + y - 1;
            int gw   = w0 + xcol - 1;
            float v  = 0.f;
            if ((unsigned)gh < HH && (unsigned)gw < WW) {
                float a = alpha[(b * CIN + ci) * TT + t];
                v = x[((b * CIN + ci) * TT + t) * (HH * WW) + gh * WW + gw] * a;
            }
            xs[cil][y][xcol] = v;
        }
        // ---- stage weight chunk, transposed to [ci][tap][co] ----
        for (int i = tid; i < COUT * CI_CHUNK * 9; i += 256) {
            int co  = i / (CI_CHUNK * 9);
            int r   = i - co * (CI_CHUNK * 9);
            int cil = r / 9;
            int tap = r - cil * 9;
            ws[cil][tap][co] = weight[(co * CIN + ci0 + cil) * 9 + tap];
        }
        __syncthreads();

        for (int cil = 0; cil < CI_CHUNK; ++cil) {
            // load 3 rows x 10 cols of x into registers (vectorized)
            float xv[3][10];
#pragma unroll
            for (int dy = 0; dy < 3; ++dy) {
                const float* p = &xs[cil][prow + dy][pcol0];
                float4 a0 = *(const float4*)p;
                float4 a1 = *(const float4*)(p + 4);
                float2 a2 = *(const float2*)(p + 8);
                xv[dy][0] = a0.x; xv[dy][1] = a0.y; xv[dy][2] = a0.z; xv[dy][3] = a0.w;
                xv[dy][4] = a1.x; xv[dy][5] = a1.y; xv[dy][6] = a1.z; xv[dy][7] = a1.w;
                xv[dy][8] = a2.x; xv[dy][9] = a2.y;
            }
#pragma unroll
            for (int ky = 0; ky < 3; ++ky) {
#pragma unroll
                for (int kx = 0; kx < 3; ++kx) {
                    const float* wp = &ws[cil][ky * 3 + kx][co0];
                    float4 w0 = *(const float4*)wp;
                    float4 w1 = *(const float4*)(wp + 4);
                    float wv[8] = {w0.x, w0.y, w0.z, w0.w, w1.x, w1.y, w1.z, w1.w};
#pragma unroll
                    for (int cc = 0; cc < 8; ++cc)
#pragma unroll
                        for (int j = 0; j < 8; ++j)
                            acc[cc][j] = fmaf(wv[cc], xv[ky][kx + j], acc[cc][j]);
                }
            }
        }
        __syncthreads();
    }

    // ---- epilogue: add bias, vectorized store ----
#pragma unroll
    for (int cc = 0; cc < 8; ++cc) {
        int co = co0 + cc;
        float bv = bias[co];
        float* op = out + ((b * COUT + co) * TT + t) * (HH * WW)
                        + (h0 + prow) * WW + (w0 + pcol0);
        float4 o0 = make_float4(acc[cc][0] + bv, acc[cc][1] + bv,
                                acc[cc][2] + bv, acc[cc][3] + bv);
        float4 o1 = make_float4(acc[cc][4] + bv, acc[cc][5] + bv,
                                acc[cc][6] + bv, acc[cc][7] + bv);
        *(float4*)op       = o0;
        *(float4*)(op + 4) = o1;
    }
}

extern "C" void kernel_launch(void* const* d_in, const int* in_sizes, int n_in,
                              void* d_out, int out_size, void* d_ws, size_t ws_size,
                              hipStream_t stream) {
    const float* x      = (const float*)d_in[0];
    const float* alpha  = (const float*)d_in[1];
    const float* weight = (const float*)d_in[2];
    const float* bias   = (const float*)d_in[3];
    float* out          = (float*)d_out;

    dim3 grid(BATCH * TT * (HH / TILE) * (WW / TILE));  // 2048 blocks
    dim3 block(256);
    hipLaunchKernelGGL(tada_conv_f32, grid, block, 0, stream,
                       x, alpha, weight, bias, out);
}

// Round 3
// 284.510 us; speedup vs baseline: 2.2874x; 2.2874x over previous
//
#include <hip/hip_runtime.h>

// TAdaConv2d via bf16 MFMA implicit GEMM. bf16 handled as raw `short` bit patterns.
//   out[b,co,t,y,w] = bias[co] + sum_{ci,ky,kx} x[b,ci,t,y+ky-1,w+kx-1]*alpha[b,ci,t]*W[co,ci,ky,kx]
// Pipeline:
//   prep_x: x (NCHW fp32) * alpha -> xhat[bt][y][w][ci] bf16, ci-inner, bank-swizzle baked in
//   prep_w: W -> wb[tap][co][slot][8] bf16 (slot = (ci>>3) ^ (co&7))
//   conv2 : per (b,t) x 2-row tile: GEMM M=64co, N=128px, K=576 with 16x16x32 bf16 MFMA

#define CIN  64
#define COUT 64
#define TT   16
#define BB   8
#define HH   64
#define WW   64

typedef __attribute__((ext_vector_type(8))) short bf16x8;
typedef __attribute__((ext_vector_type(4))) float f32x4;

__device__ __forceinline__ unsigned short f2bf(float f) {
    // round-to-nearest-even fp32 -> bf16
    union { float f; unsigned u; } v; v.f = f;
    unsigned r = (v.u + 0x7FFF + ((v.u >> 16) & 1)) >> 16;
    return (unsigned short)r;
}

// ---------------- prep_x: transpose + alpha-fold + bf16 + swizzle ----------------
// block = one (bt, h) row-plane: [ci=64][w=64] fp32 -> xhat row [w][slot][8] bf16
__global__ __launch_bounds__(256) void prep_x(const float* __restrict__ x,
                                              const float* __restrict__ alpha,
                                              int4* __restrict__ xh) {
    __shared__ float ls[64 * 66];   // [w][ci], stride 66
    const int blk = blockIdx.x;     // bt*64 + h
    const int h   = blk & 63;
    const int bt  = blk >> 6;
    const int t   = bt & 15;
    const int b   = bt >> 4;
    const int tid = threadIdx.x;

    // read coalesced: 16 lanes per ci row, float4 each; 4 iters
#pragma unroll
    for (int it = 0; it < 4; ++it) {
        int idx4 = tid + it * 256;          // 0..1023
        int ci   = idx4 >> 4;
        int w4   = (idx4 & 15) * 4;
        float a  = alpha[(b * CIN + ci) * TT + t];
        const float* gp = x + (((b * CIN + ci) * TT + t) * HH + h) * WW + w4;
        float4 v = *(const float4*)gp;
        ls[(w4 + 0) * 66 + ci] = v.x * a;
        ls[(w4 + 1) * 66 + ci] = v.y * a;
        ls[(w4 + 2) * 66 + ci] = v.z * a;
        ls[(w4 + 3) * 66 + ci] = v.w * a;
    }
    __syncthreads();

    // write: each task = (w, slot) -> 8 ci contiguous from group g = slot ^ (w&7)
#pragma unroll
    for (int it = 0; it < 2; ++it) {
        int tau  = tid + it * 256;          // 0..511
        int w    = tau >> 3;
        int slot = tau & 7;
        int g    = slot ^ (w & 7);
        const float* p = &ls[w * 66 + g * 8];
        float2 p0 = *(const float2*)(p + 0);
        float2 p1 = *(const float2*)(p + 2);
        float2 p2 = *(const float2*)(p + 4);
        float2 p3 = *(const float2*)(p + 6);
        int4 o;
        o.x = (int)f2bf(p0.x) | ((int)f2bf(p0.y) << 16);
        o.y = (int)f2bf(p1.x) | ((int)f2bf(p1.y) << 16);
        o.z = (int)f2bf(p2.x) | ((int)f2bf(p2.y) << 16);
        o.w = (int)f2bf(p3.x) | ((int)f2bf(p3.y) << 16);
        // element offset: ((bt*64 + h)*64 + w)*64 + slot*8  -> /8 for int4 index
        xh[((bt * 64 + h) * 64 + w) * 8 + slot] = o;
    }
}

// ---------------- prep_w: weight -> wb[tap][co][slot][8] bf16 ----------------
__global__ __launch_bounds__(256) void prep_w(const float* __restrict__ wgt,
                                              unsigned short* __restrict__ wb) {
    int idx = blockIdx.x * 256 + threadIdx.x;   // over co*ci*tap = 36864
    if (idx < COUT * CIN * 9) {
        int co  = idx / (CIN * 9);
        int r   = idx - co * (CIN * 9);
        int ci  = r / 9;
        int tap = r - ci * 9;
        int slot = (ci >> 3) ^ (co & 7);
        wb[((tap * COUT + co) * 8 + slot) * 8 + (ci & 7)] = f2bf(wgt[idx]);
    }
}

// ---------------- conv2: MFMA implicit GEMM ----------------
// block: (bt, ytile): 2 output rows x 64 w, all 64 co. 4 waves: (yrow 0/1) x (wseg 0/32).
__global__ __launch_bounds__(256) void conv2(const short* __restrict__ xh,
                                             const short* __restrict__ wb,
                                             const float* __restrict__ bias,
                                             float* __restrict__ out) {
    __shared__ __align__(16) short xs[4][66 * 64];   // 4 rows x (66 px x 64 ci), 33.8 KB
    __shared__ __align__(16) short wl[2][64 * 64];   // double-buffered tap weights, 16 KB

    const int blk   = blockIdx.x;
    const int ytile = blk & 31;
    const int bt    = blk >> 5;
    const int t     = bt & 15;
    const int b     = bt >> 4;
    const int y0    = ytile * 2;
    const int tid   = threadIdx.x;
    const int wave  = tid >> 6;
    const int lane  = tid & 63;

    // ---- stage x rows: wave r stages global row gy = y0-1+r ----
    {
        const int r  = wave;
        const int gy = y0 - 1 + r;
        int4* dst = (int4*)xs[r];                     // 528 int4 per row
        if ((unsigned)gy < HH) {
            const int4* src = (const int4*)(xh + (bt * 64 + gy) * 64 * 64);  // 512 int4
            int4* d = (int4*)(xs[r] + 64);            // skip left halo (64 shorts)
#pragma unroll
            for (int it = 0; it < 8; ++it) d[it * 64 + lane] = src[it * 64 + lane];
            int4 z = {0, 0, 0, 0};
            if (lane < 8)       dst[lane] = z;                    // left halo col
            else if (lane < 16) ((int4*)(xs[r] + 4160))[lane - 8] = z;  // right halo col
        } else {
            int4 z = {0, 0, 0, 0};
#pragma unroll
            for (int it = 0; it < 9; ++it) {
                int idx = it * 64 + lane;
                if (idx < 528) dst[idx] = z;
            }
        }
    }
    // ---- stage weights tap 0 ----
    {
        const int4* src = (const int4*)wb;            // tap 0: 512 int4
        int4* d = (int4*)wl[0];
        d[tid] = src[tid];
        d[tid + 256] = src[tid + 256];
    }
    __syncthreads();

    f32x4 acc[4][2] = {};
    const int ywave = wave >> 1;          // output row within tile
    const int wseg  = (wave & 1) * 32;    // pixel segment
    const int co_l  = lane & 15;
    const int kg    = lane >> 4;

    for (int tap = 0; tap < 9; ++tap) {
        const int cur = tap & 1;
        int4 wp0, wp1;
        if (tap < 8) {   // prefetch next tap into regs (store after compute)
            const int4* src = (const int4*)(wb + (tap + 1) * 4096);
            wp0 = src[tid];
            wp1 = src[tid + 256];
        }
        const int ky = tap / 3;
        const int dx = (tap - 3 * ky) - 1;
        const short* xrow = xs[ywave + ky];
        const short* wcur = wl[cur];

#pragma unroll
        for (int kc = 0; kc < 2; ++kc) {
            const int g = kc * 4 + kg;
            bf16x8 af[4];
#pragma unroll
            for (int m = 0; m < 4; ++m) {
                int co   = m * 16 + co_l;
                int slot = g ^ (co & 7);
                af[m] = *(const bf16x8*)(wcur + co * 64 + slot * 8);
            }
            bf16x8 bfr[2];
#pragma unroll
            for (int nt = 0; nt < 2; ++nt) {
                int w    = wseg + nt * 16 + co_l;
                int wx   = w + dx;                 // -1..64, halo cols are zeroed
                int slot = g ^ (wx & 7);
                bfr[nt] = *(const bf16x8*)(xrow + (wx + 1) * 64 + slot * 8);
            }
#pragma unroll
            for (int m = 0; m < 4; ++m)
#pragma unroll
                for (int nt = 0; nt < 2; ++nt)
                    acc[m][nt] = __builtin_amdgcn_mfma_f32_16x16x32_bf16(
                        af[m], bfr[nt], acc[m][nt], 0, 0, 0);
        }

        if (tap < 8) {
            int4* d = (int4*)wl[cur ^ 1];
            d[tid] = wp0;
            d[tid + 256] = wp1;
        }
        __syncthreads();
    }

    // ---- epilogue ----
    const int y = y0 + ywave;
#pragma unroll
    for (int m = 0; m < 4; ++m) {
#pragma unroll
        for (int r = 0; r < 4; ++r) {
            int co = m * 16 + (lane >> 4) * 4 + r;
            float bv = bias[co];
            float* op = out + (((b * COUT + co) * TT + t) * HH + y) * WW;
#pragma unroll
            for (int nt = 0; nt < 2; ++nt) {
                int w = wseg + nt * 16 + co_l;
                op[w] = acc[m][nt][r] + bv;
            }
        }
    }
}

extern "C" void kernel_launch(void* const* d_in, const int* in_sizes, int n_in,
                              void* d_out, int out_size, void* d_ws, size_t ws_size,
                              hipStream_t stream) {
    const float* x      = (const float*)d_in[0];
    const float* alpha  = (const float*)d_in[1];
    const float* weight = (const float*)d_in[2];
    const float* bias   = (const float*)d_in[3];
    float* out          = (float*)d_out;

    // workspace layout: [0, 128K): wb (73.7 KB used); [128K, +67.1MB): xhat
    unsigned short* wb = (unsigned short*)d_ws;
    short* xhat = (short*)((char*)d_ws + (128 << 10));

    hipLaunchKernelGGL(prep_w, dim3(144), dim3(256), 0, stream, weight, wb);
    hipLaunchKernelGGL(prep_x, dim3(BB * TT * HH), dim3(256), 0, stream,
                       x, alpha, (int4*)xhat);
    hipLaunchKernelGGL(conv2, dim3(BB * TT * (HH / 2)), dim3(256), 0, stream,
                       xhat, (const short*)wb, bias, out);
}